// Round 3
// baseline (410.028 us; speedup 1.0000x reference)
//
#include <hip/hip_runtime.h>
#include <math.h>

// Planar normalizing flow, B=524288 rows, D=64 features, F=32 flows.
// One thread per row; z held in 16 named native-vector VGPR variables (the
// round-1 float z[64] array was spilled to scratch: VGPR_Count=40, 139us).
// Flow params precomputed into workspace, read via wave-uniform scalar loads.

#define NF_D 64
#define NF_F 32

typedef float f4 __attribute__((ext_vector_type(4)));  // native clang vector

// --- Step 1: precompute u_hat[F][D] and wuh[F] = w . u_hat ---------------
__global__ void nf_precompute(const float* __restrict__ us,
                              const float* __restrict__ ws,
                              float* __restrict__ uhat,
                              float* __restrict__ wuh) {
  int f = threadIdx.x;
  if (f >= NF_F) return;
  const float* u = us + f * NF_D;
  const float* w = ws + f * NF_D;
  float wu = 0.f, n2 = 0.f;
  for (int d = 0; d < NF_D; ++d) {
    wu = fmaf(u[d], w[d], wu);
    n2 = fmaf(w[d], w[d], n2);
  }
  // softplus(wu) = max(wu,0) + log1p(exp(-|wu|))
  float sp = fmaxf(wu, 0.f) + log1pf(expf(-fabsf(wu)));
  float coef = (sp - 1.f - wu) / sqrtf(n2);   // u_hat = u + coef * w
  for (int d = 0; d < NF_D; ++d)
    uhat[f * NF_D + d] = fmaf(coef, w[d], u[d]);
  wuh[f] = fmaf(coef, n2, wu);                // w . u_hat
}

// tanh(x) = 1 - 2/(e^{2x}+1); exp2/rcp hardware approx.
// Saturates correctly: x->+inf: e=inf, rcp=0 -> 1; x->-inf: e=0 -> -1.
__device__ __forceinline__ float fast_tanh(float x) {
  float e = __builtin_amdgcn_exp2f(x * 2.885390081777927f); // 2*log2(e)
  return 1.f - 2.f * __builtin_amdgcn_rcpf(e + 1.f);
}

#define FOR16(M) M(0) M(1) M(2) M(3) M(4) M(5) M(6) M(7) \
                 M(8) M(9) M(10) M(11) M(12) M(13) M(14) M(15)

// --- Step 2: main flow, one thread per row -------------------------------
__global__ __launch_bounds__(256, 2) void nf_main(
    const float* __restrict__ x,
    const float* __restrict__ ws,
    const float* __restrict__ bs,
    const float* __restrict__ uhat,
    const float* __restrict__ wuh,
    float* __restrict__ out_z,
    float* __restrict__ out_ld,
    int B) {
  int row = blockIdx.x * blockDim.x + threadIdx.x;
  if (row >= B) return;

  const f4* __restrict__ xv =
      reinterpret_cast<const f4*>(x + (size_t)row * NF_D);

  // z in 16 named vector vars: cannot be demoted to scratch.
#define DECLZ(i) f4 z##i = xv[i];
  FOR16(DECLZ)
#undef DECLZ

  float ldp = 1.f;                       // product of (1 + h' * w.u_hat)
  for (int f = 0; f < NF_F; ++f) {       // f is wave-uniform -> scalar loads
    const f4* __restrict__ wq = reinterpret_cast<const f4*>(ws + f * NF_D);
    const f4* __restrict__ uq = reinterpret_cast<const f4*>(uhat + f * NF_D);

    f4 acc = (f4)(0.f);
#define DOT(i) { f4 w_ = wq[i];                          \
    acc.x = fmaf(z##i.x, w_.x, acc.x);                   \
    acc.y = fmaf(z##i.y, w_.y, acc.y);                   \
    acc.z = fmaf(z##i.z, w_.z, acc.z);                   \
    acc.w = fmaf(z##i.w, w_.w, acc.w); }
    FOR16(DOT)
#undef DOT
    float lin = ((acc.x + acc.y) + (acc.z + acc.w)) + bs[f];
    float h = fast_tanh(lin);

#define UPD(i) { f4 u_ = uq[i];                          \
    z##i.x = fmaf(u_.x, h, z##i.x);                      \
    z##i.y = fmaf(u_.y, h, z##i.y);                      \
    z##i.z = fmaf(u_.z, h, z##i.z);                      \
    z##i.w = fmaf(u_.w, h, z##i.w); }
    FOR16(UPD)
#undef UPD

    float hp = fmaf(-h, h, 1.f);               // 1 - h^2
    ldp *= fmaf(hp, wuh[f], 1.f);              // 1 + h' * (w.u_hat)
  }

  f4* __restrict__ ov = reinterpret_cast<f4*>(out_z + (size_t)row * NF_D);
#define STZ(i) __builtin_nontemporal_store(z##i, ov + i);
  FOR16(STZ)
#undef STZ
  // sum log|t_f| = log|prod t_f|; t in [~0.6,1.4] so the product is safe.
  float sld = __builtin_amdgcn_logf(fabsf(ldp)) * 0.6931471805599453f;
  __builtin_nontemporal_store(sld, out_ld + row);
}

extern "C" void kernel_launch(void* const* d_in, const int* in_sizes, int n_in,
                              void* d_out, int out_size, void* d_ws, size_t ws_size,
                              hipStream_t stream) {
  const float* x    = (const float*)d_in[0];
  const float* us   = (const float*)d_in[1];
  const float* ws_p = (const float*)d_in[2];
  const float* bs   = (const float*)d_in[3];
  const int B = in_sizes[0] / NF_D;

  float* uhat = (float*)d_ws;            // F*D floats
  float* wuh  = uhat + NF_F * NF_D;      // F floats
  float* out  = (float*)d_out;           // z [B*D] then sum_log_det [B]

  nf_precompute<<<1, 64, 0, stream>>>(us, ws_p, uhat, wuh);
  const int block = 256;
  const int grid = (B + block - 1) / block;
  nf_main<<<grid, block, 0, stream>>>(x, ws_p, bs, uhat, wuh,
                                      out, out + (size_t)B * NF_D, B);
}

// Round 4
// 99.000 us; speedup vs baseline: 4.1417x; 4.1417x over previous
//
#include <hip/hip_runtime.h>
#include <math.h>

// Planar normalizing flow, B=524288 rows, D=64 features, F=32 flows.
// One thread per row (params are wave-uniform -> scalar-cache s_loads).
// z kept as constant-indexed f4 z[16] (round-1 codegen: no scratch traffic).
// Dot/update written as f4 vector arithmetic to get v_pk_fma_f32 (2 FMA/inst).
// Round-3 regression (445us, +300MB writes) came from NT stores +
// launch_bounds minwaves + named-temp pipeline -> true scratch spill; all
// of those are reverted here. Single-log logdet (product form) retained.

#define NF_D 64
#define NF_F 32

typedef float f4 __attribute__((ext_vector_type(4)));

// --- Step 1: precompute u_hat[F][D] and wuh[F] = w . u_hat ---------------
__global__ void nf_precompute(const float* __restrict__ us,
                              const float* __restrict__ ws,
                              float* __restrict__ uhat,
                              float* __restrict__ wuh) {
  int f = threadIdx.x;
  if (f >= NF_F) return;
  const float* u = us + f * NF_D;
  const float* w = ws + f * NF_D;
  float wu = 0.f, n2 = 0.f;
  for (int d = 0; d < NF_D; ++d) {
    wu = fmaf(u[d], w[d], wu);
    n2 = fmaf(w[d], w[d], n2);
  }
  // softplus(wu) = max(wu,0) + log1p(exp(-|wu|))
  float sp = fmaxf(wu, 0.f) + log1pf(expf(-fabsf(wu)));
  float coef = (sp - 1.f - wu) / sqrtf(n2);   // u_hat = u + coef * w
  for (int d = 0; d < NF_D; ++d)
    uhat[f * NF_D + d] = fmaf(coef, w[d], u[d]);
  wuh[f] = fmaf(coef, n2, wu);                // w . u_hat
}

// tanh(x) = 1 - 2/(e^{2x}+1); exp2/rcp hardware approx.
// Saturates correctly: x->+inf: e=inf, rcp=0 -> 1; x->-inf: e=0 -> -1.
__device__ __forceinline__ float fast_tanh(float x) {
  float e = __builtin_amdgcn_exp2f(x * 2.885390081777927f); // 2*log2(e)
  return 1.f - 2.f * __builtin_amdgcn_rcpf(e + 1.f);
}

// --- Step 2: main flow, one thread per row -------------------------------
__global__ __launch_bounds__(256) void nf_main(
    const float* __restrict__ x,
    const float* __restrict__ ws,
    const float* __restrict__ bs,
    const float* __restrict__ uhat,
    const float* __restrict__ wuh,
    float* __restrict__ out_z,
    float* __restrict__ out_ld,
    int B) {
  int row = blockIdx.x * blockDim.x + threadIdx.x;
  if (row >= B) return;

  const f4* __restrict__ xv =
      reinterpret_cast<const f4*>(x + (size_t)row * NF_D);
  f4 z[NF_D / 4];
  #pragma unroll
  for (int i = 0; i < NF_D / 4; ++i) z[i] = xv[i];

  float ldp = 1.f;                       // product of (1 + h' * w.u_hat)
  #pragma unroll 2
  for (int f = 0; f < NF_F; ++f) {       // f is wave-uniform -> s_loads
    const f4* __restrict__ wq = reinterpret_cast<const f4*>(ws + f * NF_D);
    const f4* __restrict__ uq = reinterpret_cast<const f4*>(uhat + f * NF_D);

    f4 acc = (f4)(0.f);
    #pragma unroll
    for (int i = 0; i < NF_D / 4; ++i)
      acc += z[i] * wq[i];               // v_pk_fma_f32 pairs
    float lin = ((acc.x + acc.y) + (acc.z + acc.w)) + bs[f];
    float h = fast_tanh(lin);

    #pragma unroll
    for (int i = 0; i < NF_D / 4; ++i)
      z[i] += uq[i] * h;                 // v_pk_fma_f32 pairs

    float hp = fmaf(-h, h, 1.f);         // 1 - h^2
    ldp *= fmaf(hp, wuh[f], 1.f);        // 1 + h' * (w.u_hat)
  }

  f4* __restrict__ ov = reinterpret_cast<f4*>(out_z + (size_t)row * NF_D);
  #pragma unroll
  for (int i = 0; i < NF_D / 4; ++i) ov[i] = z[i];
  // sum log|t_f| = log|prod t_f|; t stays in [~0.6,1.1] so product is safe.
  out_ld[row] = __builtin_amdgcn_logf(fabsf(ldp)) * 0.6931471805599453f;
}

extern "C" void kernel_launch(void* const* d_in, const int* in_sizes, int n_in,
                              void* d_out, int out_size, void* d_ws, size_t ws_size,
                              hipStream_t stream) {
  const float* x    = (const float*)d_in[0];
  const float* us   = (const float*)d_in[1];
  const float* ws_p = (const float*)d_in[2];
  const float* bs   = (const float*)d_in[3];
  const int B = in_sizes[0] / NF_D;

  float* uhat = (float*)d_ws;            // F*D floats
  float* wuh  = uhat + NF_F * NF_D;      // F floats
  float* out  = (float*)d_out;           // z [B*D] then sum_log_det [B]

  nf_precompute<<<1, 64, 0, stream>>>(us, ws_p, uhat, wuh);
  const int block = 256;
  const int grid = (B + block - 1) / block;
  nf_main<<<grid, block, 0, stream>>>(x, ws_p, bs, uhat, wuh,
                                      out, out + (size_t)B * NF_D, B);
}